// Round 9
// baseline (151.393 us; speedup 1.0000x reference)
//
#include <hip/hip_runtime.h>

// B=32, T=2048, D=64, K=4, KD=256
// out[b,t,j] = m*ha + (1-m)*(g*h_fwd + (1-g)*ha)
//   d = j%64, m = M[b,t,d], delta = deltas[b,t,d] in {1..4}, clamped <= t+1
//   g = exp(-relu(delta*W[j] + b[j]))
//   h_fwd = h_a[b, t-(int(delta)-1), j]  -> one of rows t, t-1, t-2, t-3
//
// Sequential-streamer: each wave owns 8 CONSECUTIVE rows; lane owns one
// float4 of the 256-wide row (j0 = lane*4). Gather candidates for row t are
// this wave's own ha from 1-3 iterations ago -> 3 rotating registers, no
// candidate loads (3-row prologue only). Per iteration: 3 independent float4
// loads (ha/M/dl) prefetched one iteration ahead -> no dependent-address
// gather, ~2 rounds in flight per wave.

#define TD_T 2048
#define TD_KD 256
#define TD_D 64
#define RPW 8

typedef float f32x4 __attribute__((ext_vector_type(4)));

__global__ __launch_bounds__(256) void TemporalDecay_89524298318172_kernel(
    const float* __restrict__ h_a,
    const float* __restrict__ deltas,
    const float* __restrict__ M,
    const float* __restrict__ W,
    const float* __restrict__ bias,
    float* __restrict__ out)
{
    const int lane = threadIdx.x & 63;
    const int wave = (blockIdx.x * blockDim.x + threadIdx.x) >> 6;
    const int j0   = lane << 2;        // 0..252
    const int d0   = j0 & (TD_D - 1);
    const int s    = wave * RPW;       // first row (b*T + t), t0 % 8 == 0
    const int t0   = s & (TD_T - 1);
    const int hb   = s - t0;           // batch start row

    // Per-wave invariants.
    const f32x4 w4 = *(const f32x4*)(W    + j0);
    const f32x4 b4 = *(const f32x4*)(bias + j0);

    // History prologue: rows s-1..s-3 clamped into batch (clamped entries
    // can never be selected since delta <= t+1).
    const int p1 = (s - 1 > hb) ? s - 1 : hb;
    const int p2 = (s - 2 > hb) ? s - 2 : hb;
    const int p3 = (s - 3 > hb) ? s - 3 : hb;
    f32x4 h1 = *(const f32x4*)(h_a + (size_t)p1 * TD_KD + j0);
    f32x4 h2 = *(const f32x4*)(h_a + (size_t)p2 * TD_KD + j0);
    f32x4 h3 = *(const f32x4*)(h_a + (size_t)p3 * TD_KD + j0);

    // Iteration-0 loads.
    f32x4 ha = *(const f32x4*)(h_a    + (size_t)s * TD_KD + j0);
    f32x4 m4 = *(const f32x4*)(M      + (size_t)s * TD_D  + d0);
    f32x4 dl = *(const f32x4*)(deltas + (size_t)s * TD_D  + d0);

#pragma unroll
    for (int it = 0; it < RPW; ++it) {
        const int row  = s + it;
        const int nrow = (it < RPW - 1) ? row + 1 : row;  // clamped prefetch
        const f32x4 ha_n = *(const f32x4*)(h_a    + (size_t)nrow * TD_KD + j0);
        const f32x4 m_n  = *(const f32x4*)(M      + (size_t)nrow * TD_D  + d0);
        const f32x4 dl_n = *(const f32x4*)(deltas + (size_t)nrow * TD_D  + d0);

        f32x4 res;
#pragma unroll
        for (int e = 0; e < 4; ++e) {
            const float delta = dl[e];
            const float g = __expf(-fmaxf(fmaf(delta, w4[e], b4[e]), 0.0f));
            const int di = (int)delta;  // 1..4
            float hf = ha[e];
            hf = (di == 2) ? h1[e] : hf;
            hf = (di == 3) ? h2[e] : hf;
            hf = (di == 4) ? h3[e] : hf;
            const float m = m4[e];
            res[e] = m * ha[e] + (1.0f - m) * (g * hf + (1.0f - g) * ha[e]);
        }
        __builtin_nontemporal_store(res, (f32x4*)(out + (size_t)row * TD_KD + j0));

        h3 = h2; h2 = h1; h1 = ha;
        ha = ha_n; m4 = m_n; dl = dl_n;
    }
}

extern "C" void kernel_launch(void* const* d_in, const int* in_sizes, int n_in,
                              void* d_out, int out_size, void* d_ws, size_t ws_size,
                              hipStream_t stream) {
    const float* h_a    = (const float*)d_in[0];
    const float* deltas = (const float*)d_in[1];
    const float* M      = (const float*)d_in[2];
    const float* W      = (const float*)d_in[3];
    const float* bias   = (const float*)d_in[4];
    float* out          = (float*)d_out;

    // rows = B*T = 65536; one wave per 8 rows -> 8192 waves -> 2048 blocks.
    const int rows  = in_sizes[2] / TD_D;  // M has B*T*D elements
    const int waves = rows / RPW;
    const int block = 256;
    const int grid  = waves / (block / 64);
    TemporalDecay_89524298318172_kernel<<<grid, block, 0, stream>>>(
        h_a, deltas, M, W, bias, out);
}

// Round 10
// 148.332 us; speedup vs baseline: 1.0206x; 1.0206x over previous
//
#include <hip/hip_runtime.h>

// B=32, T=2048, D=64, K=4, KD=256
// out[b,t,j] = m*ha + (1-m)*(g*h_fwd + (1-g)*ha)
//   d = j%64, m = M[b,t,d], delta = deltas[b,t,d] in {1..4}, clamped <= t+1
//   g = exp(-relu(delta*W[j] + b[j]))
//   h_fwd = h_a[b, t-(int(delta)-1), j] -> one of rows t, t-1, t-2, t-3
//
// R3 structure (best measured: one row per wave, lane owns one float4, all
// candidate rows loaded at up-front-known addresses) PLUS
// amdgpu_waves_per_eu(1,4): relax the scheduler's occupancy target so it
// keeps all 8 independent loads in flight instead of register-recycling
// into serialized load->waitcnt->use rounds (R3/R4/R9 all showed VGPR<=36,
// i.e. the scheduler sank loads to uses chasing 8-waves/EU occupancy).

#define TD_T 2048
#define TD_KD 256
#define TD_D 64

typedef float f32x4 __attribute__((ext_vector_type(4)));

__global__ __launch_bounds__(256)
__attribute__((amdgpu_waves_per_eu(1, 4)))
void TemporalDecay_89524298318172_kernel(
    const float* __restrict__ h_a,
    const float* __restrict__ deltas,
    const float* __restrict__ M,
    const float* __restrict__ W,
    const float* __restrict__ bias,
    float* __restrict__ out)
{
    const int gid = blockIdx.x * blockDim.x + threadIdx.x;
    const int q   = gid & 63;        // which float4 within the 256-wide row
    const int row = gid >> 6;        // b*T + t
    const int t   = row & (TD_T - 1);
    const int j0  = q << 2;          // 0..252
    const int d0  = j0 & (TD_D - 1);

    const size_t row_off = (size_t)row * TD_KD + j0;

    // 8 independent loads -- no inter-load dependencies anywhere.
    const f32x4 ha4 = *(const f32x4*)(h_a    + row_off);
    const f32x4 m4  = *(const f32x4*)(M      + (size_t)row * TD_D + d0);
    const f32x4 dl4 = *(const f32x4*)(deltas + (size_t)row * TD_D + d0);
    const f32x4 w4  = *(const f32x4*)(W    + j0);
    const f32x4 b4  = *(const f32x4*)(bias + j0);

    const int r1 = (t >= 1) ? t - 1 : 0;
    const int r2 = (t >= 2) ? t - 2 : 0;
    const int r3 = (t >= 3) ? t - 3 : 0;
    const size_t bt_base = (size_t)(row - t) * TD_KD + j0;  // b*T*KD + j0
    const f32x4 c1 = *(const f32x4*)(h_a + bt_base + (size_t)r1 * TD_KD);
    const f32x4 c2 = *(const f32x4*)(h_a + bt_base + (size_t)r2 * TD_KD);
    const f32x4 c3 = *(const f32x4*)(h_a + bt_base + (size_t)r3 * TD_KD);

    f32x4 res;
#pragma unroll
    for (int e = 0; e < 4; ++e) {
        const float delta = dl4[e];
        const float g = __expf(-fmaxf(fmaf(delta, w4[e], b4[e]), 0.0f));
        const int di = (int)delta;  // 1..4
        float hf = ha4[e];
        hf = (di == 2) ? c1[e] : hf;
        hf = (di == 3) ? c2[e] : hf;
        hf = (di == 4) ? c3[e] : hf;
        const float m = m4[e];
        res[e] = m * ha4[e] + (1.0f - m) * (g * hf + (1.0f - g) * ha4[e]);
    }

    __builtin_nontemporal_store(res, (f32x4*)(out + row_off));
}

extern "C" void kernel_launch(void* const* d_in, const int* in_sizes, int n_in,
                              void* d_out, int out_size, void* d_ws, size_t ws_size,
                              hipStream_t stream) {
    const float* h_a    = (const float*)d_in[0];
    const float* deltas = (const float*)d_in[1];
    const float* M      = (const float*)d_in[2];
    const float* W      = (const float*)d_in[3];
    const float* bias   = (const float*)d_in[4];
    float* out          = (float*)d_out;

    // total float4 threads = B*T*KD/4 = 4,194,304
    const int total = in_sizes[0] / 4;
    const int block = 256;
    const int grid = (total + block - 1) / block;  // 16384
    TemporalDecay_89524298318172_kernel<<<grid, block, 0, stream>>>(
        h_a, deltas, M, W, bias, out);
}